// Round 10
// baseline (491.171 us; speedup 1.0000x reference)
//
#include <hip/hip_runtime.h>

typedef unsigned short u16;
typedef unsigned int u32;
typedef __attribute__((ext_vector_type(8))) short short8;
typedef __attribute__((ext_vector_type(4))) float floatx4;

#define E_TOTAL 65536

__device__ __forceinline__ u16 f2bf(float f) {
    union { float f; u32 i; } c; c.f = f;
    const u32 u = c.i;
    const u32 r = (u + 0x7fffu + ((u >> 16) & 1u)) >> 16;   // RNE, finite inputs
    return (u16)r;
}
__device__ __forceinline__ float bfu2f(u16 u) {
    union { u32 i; float f; } c; c.i = ((u32)u) << 16; return c.f;
}
// RTZ hi/lo split of two floats, packed into bf16x2 words (e0 low, e1 high).
__device__ __forceinline__ void split2(float x0, float x1, u32& hp, u32& lp) {
    union { float f; u32 u; } a0, a1, h0, h1, l0, l1;
    a0.f = x0; a1.f = x1;
    h0.u = a0.u & 0xFFFF0000u; h1.u = a1.u & 0xFFFF0000u;
    hp = __builtin_amdgcn_perm(a1.u, a0.u, 0x07060302u);    // [e0.hi16 | e1.hi16]
    l0.f = x0 - h0.f; l1.f = x1 - h1.f;                     // exact residuals
    lp = __builtin_amdgcn_perm(l1.u, l0.u, 0x07060302u);    // RTZ of residuals
}
union Frag8 { u32 u[4]; short8 s; };

// ws layout (floats): [0:768] per-graph stat sums, [768:1024] mu, [1024:1040] irs,
// [1040:1056] irv; ints [1056:1088] = binv (B-slot -> logical k pairing map)

// ---------------- Init: zero ws + probe A<->B k-slot pairing of mfma_16x16x32_bf16 ----
__global__ __launch_bounds__(64) void k_init(float* __restrict__ ws, int* __restrict__ binv) {
    const int lane = threadIdx.x;
    for (int i = lane; i < 1056; i += 64) ws[i] = 0.0f;
    const int q = lane >> 4;
    if (lane < 32) binv[lane] = lane;    // default identity (safety)
    short8 bfr;
    #pragma unroll
    for (int j = 0; j < 8; ++j) bfr[j] = (short)f2bf((float)(q*8 + j + 1));
    #pragma unroll
    for (int s = 0; s < 32; ++s) {
        const int qa = s >> 3, ja = s & 7;
        short8 afr = {0,0,0,0,0,0,0,0};
        if (q == qa) afr[ja] = (short)f2bf(1.0f);
        floatx4 dc = {0.0f, 0.0f, 0.0f, 0.0f};
        dc = __builtin_amdgcn_mfma_f32_16x16x32_bf16(afr, bfr, dc, 0, 0, 0);
        if (lane == 0) {
            const int sB = (int)(dc[0] + 0.5f) - 1;   // B-slot paired with A-slot s
            if (sB >= 0 && sB < 32) binv[sB] = s;     // logical k of that B-slot
        }
    }
}

// ---------------- Kernel 1: heavy per-edge conv, 32 edges/block, split-precision MFMA ----
// Pool reuse timeline: a_rbf(16KB) -> [barrier] -> a_h(8KB) -> [barrier] -> sh_wt(16.5KB)
__global__ __launch_bounds__(256) void k_edge_heavy(
    const float* __restrict__ node_fea, const float* __restrict__ edge_attr,
    const int* __restrict__ edge_index, const int* __restrict__ xsp,
    const float* __restrict__ w_rh, const float* __restrict__ b_rh,
    const float* __restrict__ w_ro, const float* __restrict__ b_ro,
    const float* __restrict__ w_pre, const float* __restrict__ b_pre,
    const float* __restrict__ w_sc, const float* __restrict__ w_post_s,
    const float* __restrict__ b_post_s, const float* __restrict__ w_post_v,
    const int* __restrict__ binv,
    float* __restrict__ out)
{
    __shared__ __align__(16) char pool[32 * 129 * 4];   // 16512 B, aliased
    __shared__ float sh_sin[32][81];    // s_in * (1/sqrt80), pad 81
    __shared__ float sh_vl[32][3][32];  // v_in[c][i] * (1/sqrt32)
    __shared__ float sh_acc[32][56];    // [0:24]=s_conv, [24:32]=a2(vA), [32:56]=v(o,c)
    __shared__ float sh_es0[32][16];
    __shared__ float sh_y1[32][4];
    __shared__ int   sh_kmap[32];

    u16* pool16 = (u16*)pool;
    float (*sh_wt)[129] = (float(*)[129])pool;

    const int tid = threadIdx.x;
    const int ed = tid >> 4, l16 = tid & 15;
    const int lane = tid & 63, w = tid >> 6;
    const int quad = lane >> 4, l15 = lane & 15;

    if (tid < 32) sh_kmap[tid] = binv[tid];

    const float C128 = -0.5f * (127.0f/6.0f) * (127.0f/6.0f);
    const float S128 = 6.0f/127.0f;
    const float rs80 = 0.11180339887498949f;   // 1/sqrt(80)
    const float rs32 = 0.17677669529663689f;   // 1/sqrt(32)

    int pp[2];
    // -------- prologue per edge-group g --------
    #pragma unroll
    for (int g = 0; g < 2; ++g) {
        const int e  = blockIdx.x * 32 + g*16 + ed;
        const int ge = g*16 + ed;
        const int ni = edge_index[e];
        const int nj = edge_index[E_TOTAL + e];
        pp[g] = 4*xsp[ni] + xsp[nj];
        const float4 ea = *(const float4*)(edge_attr + 4*e);
        const float d  = ea.x;
        const float vx = ea.y, vy = ea.z, vz = ea.w;
        const float invn = 1.0f / (sqrtf(vx*vx + vy*vy + vz*vz) + 1e-12f);
        if (l16 == 0) {
            sh_y1[ge][0] = 1.7320508075688772f * vx * invn;
            sh_y1[ge][1] = 1.7320508075688772f * vy * invn;
            sh_y1[ge][2] = 1.7320508075688772f * vz * invn;
        }
        // rbf -> hi/lo bf16 A-frag, tile g: elem(m,k) at (hl*2+g)*2048 + ((k>>3)*16+m)*8+(k&7)
        {
            short8 thi, tlo;
            #pragma unroll
            for (int r = 0; r < 8; ++r) {
                const int b = l16*8 + r;
                const float t = d - S128 * (float)b;
                const float x = expf(C128 * t * t);
                const u16 hi = f2bf(x);
                thi[r] = (short)hi;
                tlo[r] = (short)f2bf(x - bfu2f(hi));
            }
            *(short8*)&pool16[(0*2 + g)*2048 + (l16*16 + ed)*8] = thi;
            *(short8*)&pool16[(1*2 + g)*2048 + (l16*16 + ed)*8] = tlo;
        }
        {
            const float t = d - 0.4f * (float)l16;
            sh_es0[ge][l16] = expf(-3.125f * t * t);
        }
        {
            const float* fi = node_fea + (size_t)ni * 80;
            const float* fj = node_fea + (size_t)nj * 80;
            sh_sin[ge][2*l16+0]    = fi[2*l16+0] * rs80;
            sh_sin[ge][2*l16+1]    = fi[2*l16+1] * rs80;
            sh_sin[ge][32+2*l16+0] = fj[2*l16+0] * rs80;
            sh_sin[ge][32+2*l16+1] = fj[2*l16+1] * rs80;
            #pragma unroll
            for (int c = 0; c < 3; ++c) {
                sh_vl[ge][c][l16]      = fi[32 + 3*l16 + c] * rs32;
                sh_vl[ge][c][16 + l16] = fj[32 + 3*l16 + c] * rs32;
            }
        }
    }
    for (int s = tid; s < 32*56; s += 256) (&sh_acc[0][0])[s] = 0.0f;
    __syncthreads();

    // pairing-corrected logical k + B load offsets
    int km[8];
    u32 voff0[8], voff1[8];
    #pragma unroll
    for (int j = 0; j < 8; ++j) {
        km[j] = sh_kmap[quad*8 + j];
        voff0[j] = (u32)(km[j] * 3840 + l15);
        voff1[j] = voff0[j] + 32u * 3840u;
    }

    // edge_s (scaled, into sin[64:80]) and sc (register)
    float my_sc[2];
    #pragma unroll
    for (int g = 0; g < 2; ++g) {
        const int ge = g*16 + ed;
        const int o = l16;
        float es = b_pre[o];
        float sc = 0.0f;
        const int p = pp[g];
        #pragma unroll
        for (int i = 0; i < 16; ++i) {
            const float gg = sh_es0[ge][i];
            es += gg * w_pre[i*16 + o];
            sc += gg * w_sc[(i*16 + p)*16 + o];
        }
        sh_sin[ge][64 + o] = es * rs80;
        my_sc[g] = sc * 0.0625f;
    }

    // h = silu(rbf @ w_rh + b_rh): B loaded once, MFMAs for both tiles
    floatx4 hacc[2] = {{0,0,0,0},{0,0,0,0}};
    #pragma unroll
    for (int kk = 0; kk < 4; ++kk) {
        Frag8 bh, bl;
        #pragma unroll
        for (int jj = 0; jj < 4; ++jj) {
            const float x0 = w_rh[(size_t)(kk*32 + km[2*jj+0])*64 + w*16 + l15];
            const float x1 = w_rh[(size_t)(kk*32 + km[2*jj+1])*64 + w*16 + l15];
            split2(x0, x1, bh.u[jj], bl.u[jj]);
        }
        #pragma unroll
        for (int g = 0; g < 2; ++g) {
            const short8 ahi = *(const short8*)&pool16[(0*2 + g)*2048 + ((kk*4 + quad)*16 + l15)*8];
            const short8 alo = *(const short8*)&pool16[(1*2 + g)*2048 + ((kk*4 + quad)*16 + l15)*8];
            hacc[g] = __builtin_amdgcn_mfma_f32_16x16x32_bf16(ahi, bh.s, hacc[g], 0, 0, 0);
            hacc[g] = __builtin_amdgcn_mfma_f32_16x16x32_bf16(alo, bh.s, hacc[g], 0, 0, 0);
            hacc[g] = __builtin_amdgcn_mfma_f32_16x16x32_bf16(ahi, bl.s, hacc[g], 0, 0, 0);
        }
    }
    __syncthreads();    // a_rbf dead -> pool becomes a_h
    {
        const int hn = w*16 + l15;                // h column (= main-GEMM k)
        const float bb = b_rh[hn];
        const int k8 = hn >> 3, j2 = hn & 7;
        #pragma unroll
        for (int g = 0; g < 2; ++g) {
            #pragma unroll
            for (int r = 0; r < 4; ++r) {
                const float x = hacc[g][r] + bb;
                const float s = x / (1.0f + expf(-x));
                const int m = quad*4 + r;
                const u16 h = f2bf(s);
                pool16[(0*2 + g)*1024 + (k8*16 + m)*8 + j2] = h;
                pool16[(1*2 + g)*1024 + (k8*16 + m)*8 + j2] = f2bf(s - bfu2f(h));
            }
        }
    }
    __syncthreads();
    // A-fragments to registers: [kfrag][tile]
    short8 ah_[2][2], al_[2][2];
    #pragma unroll
    for (int f = 0; f < 2; ++f)
        #pragma unroll
        for (int g = 0; g < 2; ++g) {
            ah_[f][g] = *(const short8*)&pool16[(0*2 + g)*1024 + ((f*4 + quad)*16 + l15)*8];
            al_[f][g] = *(const short8*)&pool16[(1*2 + g)*1024 + ((f*4 + quad)*16 + l15)*8];
        }
    // (a_h reads complete before first sh_wt write: ordered by chunk-0 barrier)

    // -------- main loop: 30 chunks of 128 cols; wave w -> cols [w*32, w*32+32) --------
    for (int ch = 0; ch < 30; ++ch) {
        const int coff = ch * 128;
        floatx4 acc[2][2];       // [ct][tile]
        float bias[2];
        #pragma unroll
        for (int ct = 0; ct < 2; ++ct) {
            const int sgct = __builtin_amdgcn_readfirstlane(ch*8 + w*2 + ct);
            const float* bp = w_ro + sgct*16;
            float f0[8], f1[8];
            #pragma unroll
            for (int j = 0; j < 8; ++j) {
                f0[j] = bp[voff0[j]];
                f1[j] = bp[voff1[j]];
            }
            Frag8 b0h, b0l, b1h, b1l;
            #pragma unroll
            for (int jj = 0; jj < 4; ++jj) {
                split2(f0[2*jj], f0[2*jj+1], b0h.u[jj], b0l.u[jj]);
                split2(f1[2*jj], f1[2*jj+1], b1h.u[jj], b1l.u[jj]);
            }
            #pragma unroll
            for (int g = 0; g < 2; ++g) {
                floatx4 a = {0.0f, 0.0f, 0.0f, 0.0f};
                a = __builtin_amdgcn_mfma_f32_16x16x32_bf16(ah_[0][g], b0h.s, a, 0, 0, 0);
                a = __builtin_amdgcn_mfma_f32_16x16x32_bf16(ah_[1][g], b1h.s, a, 0, 0, 0);
                a = __builtin_amdgcn_mfma_f32_16x16x32_bf16(al_[0][g], b0h.s, a, 0, 0, 0);
                a = __builtin_amdgcn_mfma_f32_16x16x32_bf16(al_[1][g], b1h.s, a, 0, 0, 0);
                a = __builtin_amdgcn_mfma_f32_16x16x32_bf16(ah_[0][g], b0l.s, a, 0, 0, 0);
                a = __builtin_amdgcn_mfma_f32_16x16x32_bf16(ah_[1][g], b1l.s, a, 0, 0, 0);
                acc[ct][g] = a;
            }
            bias[ct] = b_ro[sgct*16 + l15];
        }
        __syncthreads();   // previous chunk's consumers done with sh_wt
        #pragma unroll
        for (int ct = 0; ct < 2; ++ct) {
            const int col = w*32 + ct*16 + l15;
            #pragma unroll
            for (int g = 0; g < 2; ++g)
                #pragma unroll
                for (int r = 0; r < 4; ++r)
                    sh_wt[g*16 + quad*4 + r][col] = acc[ct][g][r] + bias[ct];
        }
        __syncthreads();

        if (ch < 15) {          // w1: 80x24 (cols 0..1920) -> s_conv
            for (int idx = tid; idx < 768; idx += 256) {
                const int eo = idx / 24, o = idx % 24;
                const int i0 = (coff > o) ? (coff - o + 23) / 24 : 0;
                int i1 = (coff + 128 - o + 23) / 24; if (i1 > 80) i1 = 80;
                float a = 0.0f;
                for (int i = i0; i < i1; ++i)
                    a += sh_sin[eo][i] * sh_wt[eo][i*24 + o - coff];
                sh_acc[eo][o] += a;
            }
        } else if (ch < 20) {   // w2: rows ib..ib+15 (8 cols) -> a2
            const int ib = (ch - 15) * 16;
            const int eo = tid >> 3, o = tid & 7;
            float a = 0.0f;
            #pragma unroll
            for (int i = 0; i < 16; ++i)
                a += sh_sin[eo][ib + i] * sh_wt[eo][i*8 + o];
            sh_acc[eo][24 + o] += a;
        } else if (ch < 22) {   // w3: rows ib..ib+15, left = v_in[:,c]
            const int ib = (ch - 20) * 16;
            for (int idx = tid; idx < 768; idx += 256) {
                const int eo = idx / 24, rem = idx % 24;
                const int o = rem / 3, cc = rem % 3;
                float a = 0.0f;
                #pragma unroll
                for (int i = 0; i < 16; ++i)
                    a += sh_vl[eo][cc][ib + i] * sh_wt[eo][i*8 + o];
                sh_acc[eo][32 + o*3 + cc] += a;
            }
        } else if (ch < 28) {   // w4 via t-trick: q.w = Y.(vl.w)
            const int rel = coff - 2816;
            for (int idx = tid; idx < 768; idx += 256) {
                const int eo = idx / 24, o = idx % 24;
                const int i0 = (rel > o) ? (rel - o + 23) / 24 : 0;
                int i1 = (rel + 128 - o + 23) / 24; if (i1 > 32) i1 = 32;
                float t0 = 0.0f, t1 = 0.0f, t2 = 0.0f;
                for (int i = i0; i < i1; ++i) {
                    const float wv = sh_wt[eo][i*24 + o - rel];
                    t0 += sh_vl[eo][0][i] * wv;
                    t1 += sh_vl[eo][1][i] * wv;
                    t2 += sh_vl[eo][2][i] * wv;
                }
                sh_acc[eo][o] += (t0*sh_y1[eo][0] + t1*sh_y1[eo][1] + t2*sh_y1[eo][2])
                                 * 0.57735026918962573f;
            }
        } else {                // w5 via eps-trick: cross(v,Y).w = t x Y terms
            const int ib = (ch - 28) * 16;
            const int eo = tid >> 3, o = tid & 7;
            float t0 = 0.0f, t1 = 0.0f, t2 = 0.0f;
            #pragma unroll
            for (int i = 0; i < 16; ++i) {
                const float wv = sh_wt[eo][i*8 + o];
                t0 += sh_vl[eo][0][ib + i] * wv;
                t1 += sh_vl[eo][1][ib + i] * wv;
                t2 += sh_vl[eo][2][ib + i] * wv;
            }
            const float Ya = sh_y1[eo][0], Yb = sh_y1[eo][1], Yc = sh_y1[eo][2];
            sh_acc[eo][32 + o*3 + 0] += 0.70710678118654746f * (t1*Yc - t2*Yb);
            sh_acc[eo][32 + o*3 + 1] += 0.70710678118654746f * (t2*Ya - t0*Yc);
            sh_acc[eo][32 + o*3 + 2] += 0.70710678118654746f * (t0*Yb - t1*Ya);
        }
    }
    __syncthreads();

    // -------- epilogue: gate + post projections, f32 store into out --------
    #pragma unroll
    for (int g = 0; g < 2; ++g) {
        const int e  = blockIdx.x * 32 + g*16 + ed;
        const int ge = g*16 + ed;
        {
            const int o = l16;
            float a = b_post_s[o] + my_sc[g];
            #pragma unroll
            for (int i = 0; i < 16; ++i) {
                const float sv = sh_acc[ge][i];
                a += (sv / (1.0f + expf(-sv))) * w_post_s[i*16 + o];
            }
            out[(size_t)e*40 + o] = a;
        }
        if (l16 < 8) {
            const int o = l16;
            const float Ya = sh_y1[ge][0], Yb = sh_y1[ge][1], Yc = sh_y1[ge][2];
            float r0 = 0.0f, r1 = 0.0f, r2 = 0.0f;
            #pragma unroll
            for (int i = 0; i < 8; ++i) {
                const float gg = 1.0f / (1.0f + expf(-sh_acc[ge][16 + i]));
                const float a2 = sh_acc[ge][24 + i];
                const float ww = w_post_v[i*8 + o];
                r0 += (a2*Ya + sh_acc[ge][32 + i*3 + 0]) * gg * ww;
                r1 += (a2*Yb + sh_acc[ge][32 + i*3 + 1]) * gg * ww;
                r2 += (a2*Yc + sh_acc[ge][32 + i*3 + 2]) * gg * ww;
            }
            out[(size_t)e*40 + 16 + o*3 + 0] = r0;
            out[(size_t)e*40 + 16 + o*3 + 1] = r1;
            out[(size_t)e*40 + 16 + o*3 + 2] = r2;
        }
    }
}

// ---------------- Kernel 2a: per-block segment-stat partials + atomicAdd ----------------
__global__ __launch_bounds__(256) void k_stats_partial(
    const float* __restrict__ sv, const int* __restrict__ edge_index,
    const int* __restrict__ batch, float* __restrict__ ws)
{
    __shared__ float sh_ed[256][41];   // pad 41: conflict-free writes
    __shared__ int   sh_eb[256];
    const int tid = threadIdx.x;
    const int e = blockIdx.x * 256 + tid;
    sh_eb[tid] = batch[edge_index[e]];
    const float* p = sv + (size_t)e * 40;
    #pragma unroll
    for (int j = 0; j < 40; ++j) sh_ed[tid][j] = p[j];
    __syncthreads();

    for (int slot = tid; slot < 768; slot += 256) {
        const int g = slot / 48, s = slot % 48;
        float acc = 0.0f;
        if (s < 16) {
            for (int k = 0; k < 256; ++k) {
                const float m = (sh_eb[k] == g) ? 1.0f : 0.0f;
                acc += m * sh_ed[k][s];
            }
        } else if (s < 32) {
            for (int k = 0; k < 256; ++k) {
                const float m = (sh_eb[k] == g) ? 1.0f : 0.0f;
                const float v = sh_ed[k][s - 16];
                acc += m * v * v;
            }
        } else if (s < 40) {
            const int o3 = 16 + (s - 32) * 3;
            for (int k = 0; k < 256; ++k) {
                const float m = (sh_eb[k] == g) ? 1.0f : 0.0f;
                const float v0 = sh_ed[k][o3], v1 = sh_ed[k][o3+1], v2 = sh_ed[k][o3+2];
                acc += m * (v0*v0 + v1*v1 + v2*v2);
            }
        } else if (s == 40) {
            for (int k = 0; k < 256; ++k) acc += (sh_eb[k] == g) ? 1.0f : 0.0f;
        }
        atomicAdd(&ws[slot], acc);
    }
}

// ---------------- Kernel 2b: finalize per-graph mu / inv_rms ----------------
__global__ __launch_bounds__(64) void k_stats_final(float* __restrict__ ws)
{
    const int tid = threadIdx.x;
    if (tid < 16) {
        const int g = tid;
        float cnt = ws[g*48 + 40]; if (cnt < 1.0f) cnt = 1.0f;
        const float ic = 1.0f / cnt;
        float vs = 0.0f;
        for (int chn = 0; chn < 16; ++chn) {
            const float mu = ws[g*48 + chn] * ic;
            ws[768 + g*16 + chn] = mu;
            vs += ws[g*48 + 16 + chn] * ic - mu * mu;
        }
        if (vs < 0.0f) vs = 0.0f;
        ws[1024 + g] = 1.0f / sqrtf(vs * (1.0f/16.0f) + 1e-5f);
        float vv = 0.0f;
        for (int o = 0; o < 8; ++o) vv += ws[g*48 + 32 + o];
        vv = vv * ic * (1.0f/3.0f) * (1.0f/8.0f);
        ws[1040 + g] = 1.0f / sqrtf(vv + 1e-5f);
    }
}

// ---------------- Kernel 4: LN + skip + edge projections, in place on out ----------------
__global__ __launch_bounds__(256) void k_edge_final(
    float* buf, const float* __restrict__ ws,
    const float* __restrict__ edge_attr, const int* __restrict__ edge_index,
    const int* __restrict__ batch,
    const float* __restrict__ ln_w_s, const float* __restrict__ ln_b_s,
    const float* __restrict__ ln_w_v, const float* __restrict__ w_skip,
    const float* __restrict__ w_edge_s, const float* __restrict__ b_edge_s,
    const float* __restrict__ w_edge_v)
{
    __shared__ float sh_mu[16][16];
    __shared__ float sh_is[16], sh_iv[16];
    __shared__ float sh_lws[16], sh_lbs[16], sh_lwv[8];
    __shared__ float sh_skip[16][16], sh_wes[16][16], sh_bes[16], sh_wev[8][8];
    const int tid = threadIdx.x;
    sh_mu[tid >> 4][tid & 15]   = ws[768 + tid];
    sh_skip[tid >> 4][tid & 15] = w_skip[tid];
    sh_wes[tid >> 4][tid & 15]  = w_edge_s[tid];
    if (tid < 16) {
        sh_is[tid]  = ws[1024 + tid];
        sh_iv[tid]  = ws[1040 + tid];
        sh_lws[tid] = ln_w_s[tid];
        sh_lbs[tid] = ln_b_s[tid];
        sh_bes[tid] = b_edge_s[tid];
    }
    if (tid < 8)  sh_lwv[tid] = ln_w_v[tid];
    if (tid < 64) sh_wev[tid >> 3][tid & 7] = w_edge_v[tid];
    __syncthreads();

    const int e = blockIdx.x * 256 + tid;
    const int g = batch[edge_index[e]];
    const float d = edge_attr[4*e];
    float es0[16];
    #pragma unroll
    for (int b = 0; b < 16; ++b) {
        const float t = d - 0.4f * (float)b;
        es0[b] = expf(-3.125f * t * t);
    }
    float p[40];
    float* pb = buf + (size_t)e * 40;
    #pragma unroll
    for (int j = 0; j < 40; ++j) p[j] = pb[j];

    const float is = sh_is[g];
    float sn[16];
    #pragma unroll
    for (int chn = 0; chn < 16; ++chn)
        sn[chn] = (p[chn] - sh_mu[g][chn]) * is * sh_lws[chn] + sh_lbs[chn];
    #pragma unroll
    for (int b = 0; b < 16; ++b) {
        const float g0 = es0[b];
        #pragma unroll
        for (int chn = 0; chn < 16; ++chn) sn[chn] += g0 * sh_skip[b][chn];
    }
    #pragma unroll
    for (int o = 0; o < 16; ++o) {
        float a = sh_bes[o];
        #pragma unroll
        for (int chn = 0; chn < 16; ++chn) a += sn[chn] * sh_wes[chn][o];
        pb[o] = a;
    }
    const float iv = sh_iv[g];
    float vn[8][3];
    #pragma unroll
    for (int i = 0; i < 8; ++i) {
        const float f = iv * sh_lwv[i];
        vn[i][0] = p[16 + i*3 + 0] * f;
        vn[i][1] = p[16 + i*3 + 1] * f;
        vn[i][2] = p[16 + i*3 + 2] * f;
    }
    #pragma unroll
    for (int o = 0; o < 8; ++o) {
        float r0 = 0.0f, r1 = 0.0f, r2 = 0.0f;
        #pragma unroll
        for (int i = 0; i < 8; ++i) {
            const float w = sh_wev[i][o];
            r0 += vn[i][0] * w; r1 += vn[i][1] * w; r2 += vn[i][2] * w;
        }
        pb[16 + o*3 + 0] = r0;
        pb[16 + o*3 + 1] = r1;
        pb[16 + o*3 + 2] = r2;
    }
}

extern "C" void kernel_launch(void* const* d_in, const int* in_sizes, int n_in,
                              void* d_out, int out_size, void* d_ws, size_t ws_size,
                              hipStream_t stream)
{
    const float* node_fea  = (const float*)d_in[0];
    const float* edge_attr = (const float*)d_in[1];
    const int* edge_index  = (const int*)d_in[2];
    const int* xsp         = (const int*)d_in[3];
    const int* batch       = (const int*)d_in[4];
    const float* w_rh      = (const float*)d_in[5];
    const float* b_rh      = (const float*)d_in[6];
    const float* w_ro      = (const float*)d_in[7];
    const float* b_ro      = (const float*)d_in[8];
    const float* w_pre     = (const float*)d_in[9];
    const float* b_pre     = (const float*)d_in[10];
    const float* w_sc      = (const float*)d_in[11];
    const float* w_post_s  = (const float*)d_in[12];
    const float* b_post_s  = (const float*)d_in[13];
    const float* w_post_v  = (const float*)d_in[14];
    const float* ln_w_s    = (const float*)d_in[15];
    const float* ln_b_s    = (const float*)d_in[16];
    const float* ln_w_v    = (const float*)d_in[17];
    const float* w_skip    = (const float*)d_in[18];
    const float* w_edge_s  = (const float*)d_in[19];
    const float* b_edge_s  = (const float*)d_in[20];
    const float* w_edge_v  = (const float*)d_in[21];

    float* ws   = (float*)d_ws;          // 1056 floats + 32 ints (~4.3 KB)
    int*   binv = (int*)(ws + 1056);
    float* out  = (float*)d_out;

    k_init<<<1, 64, 0, stream>>>(ws, binv);
    k_edge_heavy<<<2048, 256, 0, stream>>>(node_fea, edge_attr, edge_index, xsp,
        w_rh, b_rh, w_ro, b_ro, w_pre, b_pre, w_sc, w_post_s, b_post_s, w_post_v,
        binv, out);
    k_stats_partial<<<256, 256, 0, stream>>>(out, edge_index, batch, ws);
    k_stats_final<<<1, 64, 0, stream>>>(ws);
    k_edge_final<<<256, 256, 0, stream>>>(out, ws, edge_attr, edge_index,
        batch, ln_w_s, ln_b_s, ln_w_v, w_skip, w_edge_s, b_edge_s, w_edge_v);
}